// Round 4
// baseline (37.451 us; speedup 1.0000x reference)
//
#include <hip/hip_runtime.h>
#include <stdint.h>

#define B_ 32
#define N_ 1024
#define D_ 512
#define G_ 32

typedef __attribute__((ext_vector_type(8))) short short8;
typedef __attribute__((ext_vector_type(4))) float f32x4;
union U4S8 { uint4 u; short8 s; };

// ws float-offsets:
//   [0, 524288)          : piT bf16 [32 b][32 g][1024 n]  (as u32 pairs) = 2 MB
//   [WS_M, WS_M+2097152) : K2 partials, 512 blocks x [32 g][64 m1|64 m2] = 8 MB
//   [WS_DN, +16384)      : K1 denom partials, 512 x 32
#define WS_M   524288
#define WS_DN  2621440

__device__ inline uint32_t pack_bf16x2(float a, float b) {
  uint32_t ua = __float_as_uint(a);
  uint32_t ub = __float_as_uint(b);
  ua += 0x7FFFu + ((ua >> 16) & 1u);
  ub += 0x7FFFu + ((ub >> 16) & 1u);
  return (ua >> 16) | (ub & 0xFFFF0000u);
}
__device__ inline uint16_t bf16r(float a) {
  uint32_t u = __float_as_uint(a);
  u += 0x7FFFu + ((u >> 16) & 1u);
  return (uint16_t)(u >> 16);
}

// ---------------- K1: logits MFMA + in-register softmax --------------------
// block = (b, 64-row chunk), 256 threads (4 waves). Each wave owns a 16-row
// tile, computes all 32 g. A-frags stream directly from global (no LDS, no
// barriers in K-loop). W staged once in LDS as [ks][ksub][g][8d] bf16.
__global__ __launch_bounds__(256, 2) void mdn_k1(
    const float* __restrict__ x, const float* __restrict__ W,
    const float* __restrict__ bpi, float* ws)
{
  __shared__ uint32_t Wb[8192];    // 32 KB bf16 W, frag-layout
  __shared__ uint32_t SPT[1024];   // 4 KB piT bf16 [32 g][64 r]
  __shared__ float wpart[4][32];

  const int t = threadIdx.x;
  const int bid = blockIdx.x;
  const int b = bid >> 4;
  const int n0 = (bid & 15) * 64;
  const int w = t >> 6;
  const int lane = t & 63;

  // ---- stage W once: slot = (ks*4+ksub)*32 + g, 16B per slot
  #pragma unroll
  for (int i = 0; i < 8; ++i) {
    int s = t + i * 256;             // 0..2047
    int g = s >> 6;
    int d0 = (s & 63) * 8;
    const float4* src = (const float4*)(W + g * D_ + d0);
    float4 f0 = src[0], f1 = src[1];
    int ks = d0 >> 5, ksub = (d0 >> 3) & 3;
    uint4 v;
    v.x = pack_bf16x2(f0.x, f0.y); v.y = pack_bf16x2(f0.z, f0.w);
    v.z = pack_bf16x2(f1.x, f1.y); v.w = pack_bf16x2(f1.z, f1.w);
    *(uint4*)(Wb + (size_t)(((ks * 4 + ksub) * 32 + g) * 4)) = v;
  }
  __syncthreads();

  // ---- barrier-free K-loop: load ALL A data, pack, MFMA
  const float* abase =
      x + ((size_t)(b * N_ + n0 + w * 16 + (lane & 15))) * D_ + (lane >> 4) * 8;

  f32x4 acc0 = {0.f, 0.f, 0.f, 0.f};
  f32x4 acc1 = {0.f, 0.f, 0.f, 0.f};

  float4 fa[16], fb[16];
  #pragma unroll
  for (int ks = 0; ks < 16; ++ks) {
    fa[ks] = *(const float4*)(abase + ks * 32);
    fb[ks] = *(const float4*)(abase + ks * 32 + 4);
  }
  #pragma unroll
  for (int ks = 0; ks < 16; ++ks) {
    U4S8 a;
    a.u.x = pack_bf16x2(fa[ks].x, fa[ks].y);
    a.u.y = pack_bf16x2(fa[ks].z, fa[ks].w);
    a.u.z = pack_bf16x2(fb[ks].x, fb[ks].y);
    a.u.w = pack_bf16x2(fb[ks].z, fb[ks].w);
    int idx = ((ks * 4 + (lane >> 4)) * 32 + (lane & 15)) * 4;
    U4S8 w0, w1;
    w0.u = *(uint4*)(Wb + idx);
    w1.u = *(uint4*)(Wb + idx + 64);
    acc0 = __builtin_amdgcn_mfma_f32_16x16x32_bf16(a.s, w0.s, acc0, 0, 0, 0);
    acc1 = __builtin_amdgcn_mfma_f32_16x16x32_bf16(a.s, w1.s, acc1, 0, 0, 0);
  }

  // ---- bias + in-register softmax. C layout: col g = lane&15 (acc0: g,
  // acc1: g+16), row = w*16 + (lane>>4)*4 + j. Rows live in 16-lane groups.
  float bs0 = bpi[lane & 15], bs1 = bpi[16 + (lane & 15)];
  float pi0[4], pi1[4];
  float dsum0 = 0.f, dsum1 = 0.f;
  #pragma unroll
  for (int j = 0; j < 4; ++j) {
    float v0 = acc0[j] + bs0, v1 = acc1[j] + bs1;
    float m = fmaxf(v0, v1);
    m = fmaxf(m, __shfl_xor(m, 1));
    m = fmaxf(m, __shfl_xor(m, 2));
    m = fmaxf(m, __shfl_xor(m, 4));
    m = fmaxf(m, __shfl_xor(m, 8));
    float e0 = __expf(v0 - m), e1 = __expf(v1 - m);
    float s = e0 + e1;
    s += __shfl_xor(s, 1); s += __shfl_xor(s, 2);
    s += __shfl_xor(s, 4); s += __shfl_xor(s, 8);
    float inv = 1.0f / s;
    pi0[j] = e0 * inv; pi1[j] = e1 * inv;
    dsum0 += pi0[j];   dsum1 += pi1[j];
  }
  // denom partial over this wave's 16 rows
  dsum0 += __shfl_xor(dsum0, 16); dsum0 += __shfl_xor(dsum0, 32);
  dsum1 += __shfl_xor(dsum1, 16); dsum1 += __shfl_xor(dsum1, 32);
  if (lane < 16) { wpart[w][lane] = dsum0; wpart[w][16 + lane] = dsum1; }

  // piT bf16 -> LDS transpose buffer
  {
    uint16_t* sp16 = (uint16_t*)SPT;
    int rl = w * 16 + (lane >> 4) * 4;
    #pragma unroll
    for (int j = 0; j < 4; ++j) {
      sp16[(lane & 15) * 64 + rl + j] = bf16r(pi0[j]);
      sp16[(16 + (lane & 15)) * 64 + rl + j] = bf16r(pi1[j]);
    }
  }
  __syncthreads();

  // piT global write: [b][g][n] bf16, this block's 64-n slice
  {
    int g = t >> 3, i = t & 7;
    uint4 v = *(uint4*)(SPT + g * 32 + i * 4);
    *(uint4*)((uint32_t*)ws + (size_t)(b * 32 + g) * 512 + (n0 >> 1) + i * 4) = v;
  }
  if (t < 32) {
    float s = wpart[0][t] + wpart[1][t] + wpart[2][t] + wpart[3][t];
    ws[WS_DN + bid * 32 + t] = s;
  }
}

// ---------------- K2: moments GEMM, zero-LDS zero-barrier -------------------
// block = (b, kc 256-row chunk, q 64-col o-chunk), 256 threads (4 waves).
// Wave owns o-tile w (16 cols), both g-tiles, both m1 & m2 (4 accs).
// A-frags: direct global uint4 from piT bf16. B-frags: stride-D dword gathers
// of L3-hot x (mu + sigma fetched once, feeding both m1- and m2-frags).
__global__ __launch_bounds__(256, 2) void mdn_k2(
    const float* __restrict__ x, float* ws)
{
  const int t = threadIdx.x;
  const int bid = blockIdx.x;
  const int b = bid >> 4;
  const int kc = (bid >> 2) & 3;
  const int q = bid & 3;
  const int w = t >> 6;
  const int lane = t & 63;

  const uint32_t* piT = (const uint32_t*)ws;
  const uint32_t* pa0 =
      piT + (size_t)(b * 32 + (lane & 15)) * 512 + kc * 128 + (lane >> 4) * 4;
  const uint32_t* pa1 = pa0 + 16 * 512;

  const int ocol = q * 64 + w * 16 + (lane & 15);
  const float* xb =
      x + ((size_t)(b * N_) + kc * 256 + (lane >> 4) * 8) * D_ + ocol;

  f32x4 aM10 = {0.f,0.f,0.f,0.f}, aM11 = {0.f,0.f,0.f,0.f};
  f32x4 aM20 = {0.f,0.f,0.f,0.f}, aM21 = {0.f,0.f,0.f,0.f};

  #pragma unroll
  for (int ks = 0; ks < 8; ++ks) {
    U4S8 A0, A1;
    A0.u = *(const uint4*)(pa0 + ks * 16);
    A1.u = *(const uint4*)(pa1 + ks * 16);
    const float* xp = xb + (size_t)ks * 32 * D_;
    float mu[8], sg[8];
    #pragma unroll
    for (int i = 0; i < 8; ++i) {
      mu[i] = xp[i * D_];
      sg[i] = xp[i * D_ + 256];
    }
    U4S8 Bm, B2;
    Bm.u.x = pack_bf16x2(mu[0], mu[1]); Bm.u.y = pack_bf16x2(mu[2], mu[3]);
    Bm.u.z = pack_bf16x2(mu[4], mu[5]); Bm.u.w = pack_bf16x2(mu[6], mu[7]);
    float u0 = fmaf(mu[0], mu[0], sg[0] * sg[0]);
    float u1 = fmaf(mu[1], mu[1], sg[1] * sg[1]);
    float u2 = fmaf(mu[2], mu[2], sg[2] * sg[2]);
    float u3 = fmaf(mu[3], mu[3], sg[3] * sg[3]);
    float u4 = fmaf(mu[4], mu[4], sg[4] * sg[4]);
    float u5 = fmaf(mu[5], mu[5], sg[5] * sg[5]);
    float u6 = fmaf(mu[6], mu[6], sg[6] * sg[6]);
    float u7 = fmaf(mu[7], mu[7], sg[7] * sg[7]);
    B2.u.x = pack_bf16x2(u0, u1); B2.u.y = pack_bf16x2(u2, u3);
    B2.u.z = pack_bf16x2(u4, u5); B2.u.w = pack_bf16x2(u6, u7);
    aM10 = __builtin_amdgcn_mfma_f32_16x16x32_bf16(A0.s, Bm.s, aM10, 0, 0, 0);
    aM11 = __builtin_amdgcn_mfma_f32_16x16x32_bf16(A1.s, Bm.s, aM11, 0, 0, 0);
    aM20 = __builtin_amdgcn_mfma_f32_16x16x32_bf16(A0.s, B2.s, aM20, 0, 0, 0);
    aM21 = __builtin_amdgcn_mfma_f32_16x16x32_bf16(A1.s, B2.s, aM21, 0, 0, 0);
  }

  // partial store: [32 g][64 m1 | 64 m2]; C layout col=lane&15, row=(lane>>4)*4+j
  float* dst = ws + WS_M + (size_t)bid * 4096;
  const int cl = w * 16 + (lane & 15);
  #pragma unroll
  for (int j = 0; j < 4; ++j) {
    int g0 = (lane >> 4) * 4 + j;
    dst[g0 * 128 + cl] = aM10[j];
    dst[(16 + g0) * 128 + cl] = aM11[j];
    dst[g0 * 128 + 64 + cl] = aM20[j];
    dst[(16 + g0) * 128 + 64 + cl] = aM21[j];
  }
}

// ---------------- K3: reduce partials + finalize ----------------------------
__global__ __launch_bounds__(256) void mdn_k3(
    const float* __restrict__ ws, float* __restrict__ out)
{
  __shared__ float dnm[G_];
  const int blk = blockIdx.x;
  const int b = blk >> 3, oc = blk & 7;   // oc: 32-wide o chunk
  const int t = threadIdx.x;
  if (t < G_) {
    float s = 0.f;
    #pragma unroll
    for (int c = 0; c < 16; ++c) s += ws[WS_DN + (b * 16 + c) * 32 + t];
    dnm[t] = s;
    if (oc == 0) out[b * G_ + t] = s * (1.0f / 1024.0f);   // weights
  }
  __syncthreads();
  const int g = t >> 3;
  const int o = oc * 32 + (t & 7) * 4;
  const int q = o >> 6;         // uniform per block
  const int col = o & 63;
  float4 m1 = make_float4(0.f, 0.f, 0.f, 0.f);
  float4 m2 = make_float4(0.f, 0.f, 0.f, 0.f);
  #pragma unroll
  for (int kc = 0; kc < 4; ++kc) {
    const float* p = ws + WS_M + (size_t)((b * 16 + kc * 4 + q)) * 4096 + g * 128;
    float4 a = *(const float4*)(p + col);
    float4 c2 = *(const float4*)(p + 64 + col);
    m1.x += a.x; m1.y += a.y; m1.z += a.z; m1.w += a.w;
    m2.x += c2.x; m2.y += c2.y; m2.z += c2.z; m2.w += c2.w;
  }
  float inv = 1.0f / dnm[g];
  float4 lc = make_float4(m1.x * inv, m1.y * inv, m1.z * inv, m1.w * inv);
  float4 sc;
  sc.x = sqrtf(fmaxf(m2.x * inv - lc.x * lc.x, 0.f));
  sc.y = sqrtf(fmaxf(m2.y * inv - lc.y * lc.y, 0.f));
  sc.z = sqrtf(fmaxf(m2.z * inv - lc.z * lc.z, 0.f));
  sc.w = sqrtf(fmaxf(m2.w * inv - lc.w * lc.w, 0.f));
  float* scales = out + 1024;
  float* locs = out + 1024 + 262144;
  int oi = ((b * G_ + g) << 8) + o;
  *(float4*)(scales + oi) = sc;
  *(float4*)(locs + oi) = lc;
}

extern "C" void kernel_launch(void* const* d_in, const int* in_sizes, int n_in,
                              void* d_out, int out_size, void* d_ws, size_t ws_size,
                              hipStream_t stream)
{
  const float* x = (const float*)d_in[0];
  const float* W = (const float*)d_in[1];
  const float* bpi = (const float*)d_in[2];
  float* out = (float*)d_out;
  float* ws = (float*)d_ws;
  hipLaunchKernelGGL(mdn_k1, dim3(512), dim3(256), 0, stream, x, W, bpi, ws);
  hipLaunchKernelGGL(mdn_k2, dim3(512), dim3(256), 0, stream, x, ws);
  hipLaunchKernelGGL(mdn_k3, dim3(256), dim3(256), 0, stream, ws, out);
}